// Round 20
// baseline (90.286 us; speedup 1.0000x reference)
//
#include <hip/hip_runtime.h>

typedef __bf16 bf16_t;
typedef __bf16 bf16x8 __attribute__((ext_vector_type(8)));
typedef __bf16 bf16x4 __attribute__((ext_vector_type(4)));
typedef short  s16x4  __attribute__((ext_vector_type(4)));
typedef float  f32x4  __attribute__((ext_vector_type(4)));
typedef unsigned int u32;

#define BB 2
#define SS 2048
#define EE 768
#define HH 12
#define DD 64
#define NROW (BB*SS)   // 4096

// async global->LDS, 16B per lane. LDS dest = firstlane(base)+lane*16 (linear).
#define GLDS16(gp, lp) __builtin_amdgcn_global_load_lds( \
    (const __attribute__((address_space(1))) u32*)(gp),   \
    (__attribute__((address_space(3))) u32*)(lp), 16, 0, 0)

#if __has_builtin(__builtin_amdgcn_mfma_f32_16x16x16bf16_1k)
#define MFMA16_BUILTIN 1
static __device__ __forceinline__ f32x4 mfma_16x16x16_bf16(bf16x4 a, bf16x4 b, f32x4 c) {
  return __builtin_amdgcn_mfma_f32_16x16x16bf16_1k(
      __builtin_bit_cast(s16x4, a), __builtin_bit_cast(s16x4, b), c, 0, 0, 0);
}
#else
#define MFMA16_BUILTIN 0
static __device__ __forceinline__ f32x4 mfma_16x16x16_bf16(bf16x4 a, bf16x4 b, f32x4 c) {
  asm volatile("v_mfma_f32_16x16x16_bf16 %0, %1, %2, %0" : "+v"(c) : "v"(a), "v"(b));
  return c;
}
#endif

// ---------------- prep: pack weights (blocks 0..575) + LayerNorm (blocks 576..1599) ----------------
__global__ __launch_bounds__(256) void prep_kernel(
    const float* __restrict__ wq, const float* __restrict__ wk,
    const float* __restrict__ wv, const float* __restrict__ wo,
    bf16_t* __restrict__ wt,
    const float* __restrict__ x, const float* __restrict__ lnw,
    const float* __restrict__ lnb, bf16_t* __restrict__ xn)
{
  const int bid = blockIdx.x;
  if (bid < 576) {
    // pack path: wt[z][n][k] = w_z[k][n] (bf16)
    __shared__ float tile[64][65];
    const int z = bid / 144, rem = bid % 144;
    const int k0 = (rem/12)*64, n0 = (rem%12)*64;
    const float* src = (z==0)?wq:(z==1)?wk:(z==2)?wv:wo;
    const int t = threadIdx.x;
    #pragma unroll
    for (int it=0; it<16; ++it) {
      int idx = it*256+t, r = idx>>6, c = idx&63;
      tile[r][c] = src[(size_t)(k0+r)*EE + n0 + c];
    }
    __syncthreads();
    bf16_t* dst = wt + (size_t)z*EE*EE;
    #pragma unroll
    for (int it=0; it<16; ++it) {
      int idx = it*256+t, r = idx>>6, c = idx&63;
      dst[(size_t)(n0+r)*EE + k0 + c] = (bf16_t)tile[c][r];
    }
  } else {
    // LayerNorm path: wave-per-row, no LDS, no barrier
    const int row  = (bid - 576)*4 + (threadIdx.x>>6);
    const int lane = threadIdx.x & 63;
    const float* xr = x + (size_t)row*EE + lane*4;
    f32x4 v0 = *(const f32x4*)(xr);
    f32x4 v1 = *(const f32x4*)(xr + 256);
    f32x4 v2 = *(const f32x4*)(xr + 512);
    float s = 0.f, ss = 0.f;
    #pragma unroll
    for (int i=0;i<4;++i) {
      s  += v0[i] + v1[i] + v2[i];
      ss += v0[i]*v0[i] + v1[i]*v1[i] + v2[i]*v2[i];
    }
    #pragma unroll
    for (int m=1; m<64; m<<=1) { s += __shfl_xor(s,m); ss += __shfl_xor(ss,m); }
    const float mu   = s*(1.0f/EE);
    const float rstd = rsqrtf(ss*(1.0f/EE) - mu*mu + 1e-5f);
    bf16_t* xo = xn + (size_t)row*EE + lane*4;
    #pragma unroll
    for (int k=0;k<3;++k) {
      const f32x4 v = (k==0)?v0:(k==1)?v1:v2;
      bf16x4 o;
      #pragma unroll
      for (int i=0;i<4;++i)
        o[i] = (bf16_t)((v[i]-mu)*rstd*lnw[k*256 + lane*4 + i] + lnb[k*256 + lane*4 + i]);
      *(bf16x4*)(xo + k*256) = o;
    }
  }
}

// ---------------- QKV GEMM: BM=128 BN=48 -> 32x48 = 1536 blocks (6/CU) ----------------
// Same occupancy treatment that won on gemm_out: short-K GEMMs here are
// staging-latency-bound; more resident blocks hide it. 4-way row-split waves.
__global__ __launch_bounds__(256) void gemm_qkv_kernel(
    const bf16_t* __restrict__ xn, const bf16_t* __restrict__ wt,
    const float* __restrict__ bq, const float* __restrict__ bk, const float* __restrict__ bv,
    bf16_t* __restrict__ qb, bf16_t* __restrict__ kb, bf16_t* __restrict__ vb)
{
  __shared__ __align__(16) bf16_t As[2][128][32];
  __shared__ __align__(16) bf16_t Bs[2][48][32];
  const int bm = blockIdx.x, by = blockIdx.y;
  const int mat = by >> 4, nb = by & 15;      // 16 panels of 48 per matrix
  const bf16_t* W = wt + (size_t)mat*EE*EE + (size_t)nb*48*EE;
  const float* bias = (mat==0)?bq:(mat==1)?bk:bv;
  bf16_t* outp = (mat==0)?qb:(mat==1)?kb:vb;
  const int t = threadIdx.x, lane = t&63, wid = t>>6;
  const int lrow = lane&15, lk = lane>>4;
  const bf16_t* Ag = xn + (size_t)bm*128*EE;

  const int srow = t>>2, sp = t&3;
  const int sg = sp ^ ((srow>>1)&3);
  const int pcs = (lrow>>1)&3;

  auto stage = [&](int buf, int k0) {
    const bf16_t* asrc = Ag + (size_t)srow*EE + k0 + sg*8;
    GLDS16(asrc,                 &As[buf][0][0] + t*8);
    GLDS16(asrc + (size_t)64*EE, &As[buf][0][0] + 2048 + t*8);
    if (t < 192)   // 48 rows x 4 chunks (waves 0-2, wave-uniform guard)
      GLDS16(W + (size_t)srow*EE + k0 + sg*8, &Bs[buf][0][0] + t*8);
  };

  f32x4 acc[2][3];
  #pragma unroll
  for (int i=0;i<2;++i)
    #pragma unroll
    for (int j=0;j<3;++j) acc[i][j] = (f32x4){0.f,0.f,0.f,0.f};

  stage(0, 0);
  __syncthreads();
  int cur = 0;
  for (int k0=0; k0<EE; k0+=32) {
    if (k0+32 < EE) stage(cur^1, k0+32);
    bf16x8 af[2], bfv[3];
    #pragma unroll
    for (int mi=0;mi<2;++mi) af[mi]  = *(const bf16x8*)&As[cur][wid*32+mi*16+lrow][(lk^pcs)*8];
    #pragma unroll
    for (int ni=0;ni<3;++ni) bfv[ni] = *(const bf16x8*)&Bs[cur][ni*16+lrow][(lk^pcs)*8];
    #pragma unroll
    for (int mi=0;mi<2;++mi)
      #pragma unroll
      for (int ni=0;ni<3;++ni)
        acc[mi][ni] = __builtin_amdgcn_mfma_f32_16x16x32_bf16(af[mi], bfv[ni], acc[mi][ni], 0,0,0);
    __syncthreads();
    cur ^= 1;
  }
  const int m_base = bm*128 + wid*32;
  const int n_base = nb*48;
  #pragma unroll
  for (int ni=0;ni<3;++ni) {
    const int col = n_base + ni*16 + lrow;
    const float bias_v = bias[col];
    #pragma unroll
    for (int mi=0;mi<2;++mi) {
      #pragma unroll
      for (int r=0;r<4;++r) {
        int row = m_base + mi*16 + 4*lk + r;
        outp[(size_t)row*EE + col] = (bf16_t)(acc[mi][ni][r] + bias_v);
      }
    }
  }
}

// ---------------- V transpose: v[b,s,h,d] -> vt[(b*H+h)*D + d][s] ----------------
__global__ __launch_bounds__(256) void vtrans_kernel(
    const bf16_t* __restrict__ v, bf16_t* __restrict__ vt)
{
  __shared__ __align__(16) bf16_t tile[64][72];
  const int j0 = blockIdx.x*64, bh = blockIdx.y;
  const int b = bh/HH, h = bh%HH;
  const int t = threadIdx.x;
  #pragma unroll
  for (int it=0; it<2; ++it) {
    int idx = it*256+t, r = idx>>3, c8 = (idx&7)*8;
    *(bf16x8*)&tile[r][c8] = *(const bf16x8*)(v + (size_t)(b*SS + j0 + r)*EE + h*DD + c8);
  }
  __syncthreads();
  #pragma unroll
  for (int it=0; it<2; ++it) {
    int idx = it*256+t, d = idx>>3, c8 = (idx&7)*8;
    bf16x8 val;
    #pragma unroll
    for (int i=0;i<8;++i) val[i] = tile[c8+i][d];
    *(bf16x8*)(vt + ((size_t)bh*DD + d)*SS + j0 + c8) = val;
  }
}

// ---------------- flash attention (anti-causal: attend j >= i) ----------------
// R12 configuration EXACT (best measured). Q-resident j-split: 4 waves, 64
// q-rows/block; each wave holds 4 q-groups' Q fragments in registers and owns
// a 16-j slice of every staged tile. Fixed-max softmax (p=e^(S-24), additive).
__global__ __launch_bounds__(256, 3) void attn_kernel(
    const bf16_t* __restrict__ qb, const bf16_t* __restrict__ kb,
    const bf16_t* __restrict__ vt, bf16_t* __restrict__ hb)
{
  __shared__ __align__(16) bf16_t Ks[2][64][64];   // K tile [j][d]
  __shared__ __align__(16) bf16_t Vts[2][64][64];  // V^T tile [d][j]
  __shared__ __align__(16) float  Osum[64][68];    // O merge [q][d] (+pad)
  __shared__ float Lsum[4][64];                    // lsum partial [wave][q]

  // snake remap: blocks bid, bid+256, bid+512 share a CU -> complementary work
  const int bid = blockIdx.x;
  const int rnd = bid >> 8, g8 = bid & 255;
  const int item = (rnd == 1) ? (511 - g8) : (rnd*256 + g8);
  const int qt = item / 24, bh = item % 24;

  const int i0 = qt*64, b = bh/HH, h = bh%HH;
  const int t = threadIdx.x, lane = t&63, w = t>>6;   // w = wave id = j-slice
  const int lrow = lane&15, lk = lane>>4;

  const int sr = t>>3, sp = t&7;
  const int sgc = sp ^ (sr&7);
  const bf16_t* kbase  = kb + (size_t)b*SS*EE + h*DD;
  const bf16_t* vtbase = vt + (size_t)bh*DD*SS;

  // Q fragments (B-operand), 4 groups of 16 q-rows — loop-invariant registers
  bf16x8 qf[4][2];
  #pragma unroll
  for (int g=0; g<4; ++g) {
    const bf16_t* qrow = qb + (size_t)(b*SS + i0 + g*16 + lrow)*EE + h*DD;
    qf[g][0] = *(const bf16x8*)(qrow + lk*8);
    qf[g][1] = *(const bf16x8*)(qrow + 32 + lk*8);
  }

  f32x4 acc[4][4];
  #pragma unroll
  for (int g=0; g<4; ++g)
    #pragma unroll
    for (int i=0;i<4;++i) acc[g][i] = (f32x4){0.f,0.f,0.f,0.f};
  float lsum[4] = {0.f,0.f,0.f,0.f};
  const int kkey = lrow&7;

  auto stage = [&](int buf, int jt) {
    const int j0v = jt*64;
    const bf16_t* ksrc = kbase  + (size_t)(j0v + sr)*EE + sgc*8;
    const bf16_t* vsrc = vtbase + (size_t)sr*SS + j0v + sgc*8;
    GLDS16(ksrc,                 &Ks[buf][0][0]  + t*8);
    GLDS16(ksrc + (size_t)32*EE, &Ks[buf][0][0]  + 2048 + t*8);
    GLDS16(vsrc,                 &Vts[buf][0][0] + t*8);
    GLDS16(vsrc + (size_t)32*SS, &Vts[buf][0][0] + 2048 + t*8);
  };

  // Per tile, this wave covers j-local = w*16 + 4*lk + r (its 16-j slice).
  // p = e^(qk/8 - 24) = 2^(a*0.1803369 - 34.62468); fixed max -> additive
#define ATTN_TILE(CUR, MASKED) do {                                          \
    const bf16_t* krow = &Ks[CUR][w*16 + lrow][0];                           \
    bf16x8 kf0 = *(const bf16x8*)(krow + ((lk^kkey)<<3));                    \
    bf16x8 kf1 = *(const bf16x8*)(krow + (((lk+4)^kkey)<<3));                \
    bf16x4 pb[4];                                                            \
    _Pragma("unroll")                                                        \
    for (int g=0; g<4; ++g) {                                                \
      f32x4 a = (f32x4){0.f,0.f,0.f,0.f};                                    \
      a = __builtin_amdgcn_mfma_f32_16x16x32_bf16(kf0, qf[g][0], a, 0,0,0);  \
      a = __builtin_amdgcn_mfma_f32_16x16x32_bf16(kf1, qf[g][1], a, 0,0,0);  \
      _Pragma("unroll")                                                      \
      for (int r=0;r<4;++r) {                                                \
        float ee = a[r]*0.180336878f - 34.6246784f;                          \
        if (MASKED && (w*16 + 4*lk + r) < (g*16 + lrow)) ee = -1e30f;        \
        float p = exp2f(ee);                                                 \
        lsum[g] += p;                                                        \
        pb[g][r] = (bf16_t)p;                                                \
      }                                                                      \
    }                                                                        \
    _Pragma("unroll")                                                        \
    for (int sd=0;sd<4;++sd) {                                               \
      const bf16_t* vrow = &Vts[CUR][sd*16+lrow][0];                         \
      bf16x4 vf = *(const bf16x4*)(vrow + (((2*w+(lk>>1))^kkey)<<3) + ((lk&1)<<2)); \
      _Pragma("unroll")                                                      \
      for (int g=0; g<4; ++g)                                                \
        acc[g][sd] = mfma_16x16x16_bf16(vf, pb[g], acc[g][sd]);              \
    }                                                                        \
  } while(0)

  const int ntiles = SS/64 - qt;  // 1..32
  stage(0, qt);
  __syncthreads();                 // buf0 ready
  if (ntiles > 1) stage(1, qt+1);  // prefetch flies under diagonal compute
  ATTN_TILE(0, true);              // diagonal tile, masked
#if !MFMA16_BUILTIN
  asm volatile("s_nop 7\n\ts_nop 7");
#endif
  __syncthreads();

  int cur = 1;
  for (int it2=1; it2<ntiles; ++it2) {
    if (it2+1 < ntiles) stage(cur^1, qt+it2+1);
    ATTN_TILE(cur, false);
#if !MFMA16_BUILTIN
    asm volatile("s_nop 7\n\ts_nop 7");
#endif
    __syncthreads();
    cur ^= 1;
  }
#undef ATTN_TILE

  // lsum: reduce across lk (j within slice); store per-wave partials
  #pragma unroll
  for (int g=0; g<4; ++g) {
    lsum[g] += __shfl_xor(lsum[g], 16);
    lsum[g] += __shfl_xor(lsum[g], 32);
  }
  if (lane < 16) {
    #pragma unroll
    for (int g=0; g<4; ++g) Lsum[w][g*16 + lane] = lsum[g];
  }

  // O merge across waves (each holds a j-partial of the FULL 64q x 64d tile)
  __syncthreads();
  if (w == 0) {
    #pragma unroll
    for (int g=0; g<4; ++g)
      #pragma unroll
      for (int sd=0; sd<4; ++sd)
        *(f32x4*)&Osum[g*16+lrow][sd*16 + 4*lk] = acc[g][sd];
  }
  __syncthreads();
  if (w == 1) {
    #pragma unroll
    for (int g=0; g<4; ++g)
      #pragma unroll
      for (int sd=0; sd<4; ++sd) {
        f32x4 v = *(f32x4*)&Osum[g*16+lrow][sd*16 + 4*lk];
        *(f32x4*)&Osum[g*16+lrow][sd*16 + 4*lk] = v + acc[g][sd];
      }
  }
  __syncthreads();
  if (w == 2) {
    #pragma unroll
    for (int g=0; g<4; ++g)
      #pragma unroll
      for (int sd=0; sd<4; ++sd) {
        f32x4 v = *(f32x4*)&Osum[g*16+lrow][sd*16 + 4*lk];
        *(f32x4*)&Osum[g*16+lrow][sd*16 + 4*lk] = v + acc[g][sd];
      }
  }
  __syncthreads();
  if (w == 3) {
    #pragma unroll
    for (int g=0; g<4; ++g)
      #pragma unroll
      for (int sd=0; sd<4; ++sd) {
        f32x4 v = *(f32x4*)&Osum[g*16+lrow][sd*16 + 4*lk];
        *(f32x4*)&Osum[g*16+lrow][sd*16 + 4*lk] = v + acc[g][sd];
      }
  }
  __syncthreads();

  // final: normalize + coalesced bf16 store (thread t: q = t>>2, 16 d each)
  const int q = t>>2, dq = t&3;
  const float ltot = Lsum[0][q] + Lsum[1][q] + Lsum[2][q] + Lsum[3][q];
  const float inv = 1.0f / ltot;
  bf16_t* orow = hb + (size_t)(b*SS + i0 + q)*EE + h*DD + dq*16;
  bf16x8 o0, o1;
  #pragma unroll
  for (int c=0;c<2;++c) {
    f32x4 v0 = *(const f32x4*)&Osum[q][dq*16 + c*8];
    f32x4 v1 = *(const f32x4*)&Osum[q][dq*16 + c*8 + 4];
    #pragma unroll
    for (int i=0;i<4;++i) {
      if (c==0) { o0[i] = (bf16_t)(v0[i]*inv); o0[i+4] = (bf16_t)(v1[i]*inv); }
      else      { o1[i] = (bf16_t)(v0[i]*inv); o1[i+4] = (bf16_t)(v1[i]*inv); }
    }
  }
  *(bf16x8*)orow = o0;
  *(bf16x8*)(orow+8) = o1;
}

// ---------------- output GEMM: BM=64 BN=48 -> 64x16 = 1024 blocks (4/CU) ----------------
__global__ __launch_bounds__(256) void gemm_out_kernel(
    const bf16_t* __restrict__ hbuf, const bf16_t* __restrict__ wto,
    const float* __restrict__ bo, float* __restrict__ out)
{
  __shared__ __align__(16) bf16_t As[2][64][32];
  __shared__ __align__(16) bf16_t Bs[2][48][32];
  const int bm = blockIdx.x, nb = blockIdx.y;
  const bf16_t* W = wto + (size_t)nb*48*EE;
  const int t = threadIdx.x, lane = t&63, wid = t>>6;
  const int lrow = lane&15, lk = lane>>4;
  const bf16_t* Ag = hbuf + (size_t)bm*64*EE;

  const int srow = t>>2, sp = t&3;
  const int sg = sp ^ ((srow>>1)&3);
  const int pcs = (lrow>>1)&3;

  auto stage = [&](int buf, int k0) {
    GLDS16(Ag + (size_t)srow*EE + k0 + sg*8, &As[buf][0][0] + t*8);
    if (t < 192)
      GLDS16(W + (size_t)srow*EE + k0 + sg*8, &Bs[buf][0][0] + t*8);
  };

  f32x4 acc[3];
  #pragma unroll
  for (int j=0;j<3;++j) acc[j] = (f32x4){0.f,0.f,0.f,0.f};

  stage(0, 0);
  __syncthreads();
  int cur = 0;
  for (int k0=0; k0<EE; k0+=32) {
    if (k0+32 < EE) stage(cur^1, k0+32);
    bf16x8 af, bfv[3];
    af = *(const bf16x8*)&As[cur][wid*16+lrow][(lk^pcs)*8];
    #pragma unroll
    for (int ni=0;ni<3;++ni) bfv[ni] = *(const bf16x8*)&Bs[cur][ni*16+lrow][(lk^pcs)*8];
    #pragma unroll
    for (int ni=0;ni<3;++ni)
      acc[ni] = __builtin_amdgcn_mfma_f32_16x16x32_bf16(af, bfv[ni], acc[ni], 0,0,0);
    __syncthreads();
    cur ^= 1;
  }
  const int m_base = bm*64 + wid*16;
  const int n_base = nb*48;
  #pragma unroll
  for (int ni=0;ni<3;++ni) {
    const int col = n_base + ni*16 + lrow;
    const float bias_v = bo[col];
    #pragma unroll
    for (int r=0;r<4;++r) {
      int row = m_base + 4*lk + r;
      out[(size_t)row*EE + col] = acc[ni][r] + bias_v;
    }
  }
}

extern "C" void kernel_launch(void* const* d_in, const int* in_sizes, int n_in,
                              void* d_out, int out_size, void* d_ws, size_t ws_size,
                              hipStream_t stream) {
  const float* x    = (const float*)d_in[0];
  const float* ln_w = (const float*)d_in[1];
  const float* ln_b = (const float*)d_in[2];
  const float* wq   = (const float*)d_in[3];
  const float* bq   = (const float*)d_in[4];
  const float* wk   = (const float*)d_in[5];
  const float* bk   = (const float*)d_in[6];
  const float* wv   = (const float*)d_in[7];
  const float* bv   = (const float*)d_in[8];
  const float* wo   = (const float*)d_in[9];
  const float* bo   = (const float*)d_in[10];
  float* out = (float*)d_out;

  char* ws = (char*)d_ws;
  bf16_t* wt  = (bf16_t*)(ws);
  bf16_t* xn  = (bf16_t*)(ws + 4718592);
  bf16_t* qb  = (bf16_t*)(ws + 11010048);
  bf16_t* kb  = (bf16_t*)(ws + 17301504);
  bf16_t* vb  = (bf16_t*)(ws + 23592960);
  bf16_t* vtb = (bf16_t*)(ws + 29884416);
  bf16_t* hb  = (bf16_t*)(ws + 36175872);

  prep_kernel    <<<dim3(1600),    256, 0, stream>>>(wq, wk, wv, wo, wt, x, ln_w, ln_b, xn);
  gemm_qkv_kernel<<<dim3(32,48),   256, 0, stream>>>(xn, wt, bq, bk, bv, qb, kb, vb);
  vtrans_kernel  <<<dim3(32,24),   256, 0, stream>>>(vb, vtb);
  attn_kernel    <<<dim3(768),     256, 0, stream>>>(qb, kb, vtb, hb);
  gemm_out_kernel<<<dim3(64,16),   256, 0, stream>>>(hb, wt + (size_t)3*EE*EE, bo, out);
}

// Round 21
// 82.670 us; speedup vs baseline: 1.0921x; 1.0921x over previous
//
#include <hip/hip_runtime.h>

typedef __bf16 bf16_t;
typedef __bf16 bf16x8 __attribute__((ext_vector_type(8)));
typedef __bf16 bf16x4 __attribute__((ext_vector_type(4)));
typedef short  s16x4  __attribute__((ext_vector_type(4)));
typedef float  f32x4  __attribute__((ext_vector_type(4)));
typedef unsigned int u32;

#define BB 2
#define SS 2048
#define EE 768
#define HH 12
#define DD 64
#define NROW (BB*SS)   // 4096

// async global->LDS, 16B per lane. LDS dest = firstlane(base)+lane*16 (linear).
#define GLDS16(gp, lp) __builtin_amdgcn_global_load_lds( \
    (const __attribute__((address_space(1))) u32*)(gp),   \
    (__attribute__((address_space(3))) u32*)(lp), 16, 0, 0)

#if __has_builtin(__builtin_amdgcn_mfma_f32_16x16x16bf16_1k)
#define MFMA16_BUILTIN 1
static __device__ __forceinline__ f32x4 mfma_16x16x16_bf16(bf16x4 a, bf16x4 b, f32x4 c) {
  return __builtin_amdgcn_mfma_f32_16x16x16bf16_1k(
      __builtin_bit_cast(s16x4, a), __builtin_bit_cast(s16x4, b), c, 0, 0, 0);
}
#else
#define MFMA16_BUILTIN 0
static __device__ __forceinline__ f32x4 mfma_16x16x16_bf16(bf16x4 a, bf16x4 b, f32x4 c) {
  asm volatile("v_mfma_f32_16x16x16_bf16 %0, %1, %2, %0" : "+v"(c) : "v"(a), "v"(b));
  return c;
}
#endif

// ---------------- prep: pack weights (blocks 0..575) + LayerNorm (blocks 576..1599) ----------------
__global__ __launch_bounds__(256) void prep_kernel(
    const float* __restrict__ wq, const float* __restrict__ wk,
    const float* __restrict__ wv, const float* __restrict__ wo,
    bf16_t* __restrict__ wt,
    const float* __restrict__ x, const float* __restrict__ lnw,
    const float* __restrict__ lnb, bf16_t* __restrict__ xn)
{
  const int bid = blockIdx.x;
  if (bid < 576) {
    // pack path: wt[z][n][k] = w_z[k][n] (bf16)
    __shared__ float tile[64][65];
    const int z = bid / 144, rem = bid % 144;
    const int k0 = (rem/12)*64, n0 = (rem%12)*64;
    const float* src = (z==0)?wq:(z==1)?wk:(z==2)?wv:wo;
    const int t = threadIdx.x;
    #pragma unroll
    for (int it=0; it<16; ++it) {
      int idx = it*256+t, r = idx>>6, c = idx&63;
      tile[r][c] = src[(size_t)(k0+r)*EE + n0 + c];
    }
    __syncthreads();
    bf16_t* dst = wt + (size_t)z*EE*EE;
    #pragma unroll
    for (int it=0; it<16; ++it) {
      int idx = it*256+t, r = idx>>6, c = idx&63;
      dst[(size_t)(n0+r)*EE + k0 + c] = (bf16_t)tile[c][r];
    }
  } else {
    // LayerNorm path: wave-per-row, no LDS, no barrier
    const int row  = (bid - 576)*4 + (threadIdx.x>>6);
    const int lane = threadIdx.x & 63;
    const float* xr = x + (size_t)row*EE + lane*4;
    f32x4 v0 = *(const f32x4*)(xr);
    f32x4 v1 = *(const f32x4*)(xr + 256);
    f32x4 v2 = *(const f32x4*)(xr + 512);
    float s = 0.f, ss = 0.f;
    #pragma unroll
    for (int i=0;i<4;++i) {
      s  += v0[i] + v1[i] + v2[i];
      ss += v0[i]*v0[i] + v1[i]*v1[i] + v2[i]*v2[i];
    }
    #pragma unroll
    for (int m=1; m<64; m<<=1) { s += __shfl_xor(s,m); ss += __shfl_xor(ss,m); }
    const float mu   = s*(1.0f/EE);
    const float rstd = rsqrtf(ss*(1.0f/EE) - mu*mu + 1e-5f);
    bf16_t* xo = xn + (size_t)row*EE + lane*4;
    #pragma unroll
    for (int k=0;k<3;++k) {
      const f32x4 v = (k==0)?v0:(k==1)?v1:v2;
      bf16x4 o;
      #pragma unroll
      for (int i=0;i<4;++i)
        o[i] = (bf16_t)((v[i]-mu)*rstd*lnw[k*256 + lane*4 + i] + lnb[k*256 + lane*4 + i]);
      *(bf16x4*)(xo + k*256) = o;
    }
  }
}

// ---------------- QKV GEMM: BM=128 BN=96 -> 32x24 = 768 blocks (R12/R19 verbatim) ----------------
__global__ __launch_bounds__(256) void gemm_qkv_kernel(
    const bf16_t* __restrict__ xn, const bf16_t* __restrict__ wt,
    const float* __restrict__ bq, const float* __restrict__ bk, const float* __restrict__ bv,
    bf16_t* __restrict__ qb, bf16_t* __restrict__ kb, bf16_t* __restrict__ vb)
{
  __shared__ __align__(16) bf16_t As[2][128][32];
  __shared__ __align__(16) bf16_t Bs[2][96][32];
  const int bm = blockIdx.x, by = blockIdx.y;
  const int mat = by >> 3, nb = by & 7;
  const bf16_t* W = wt + (size_t)mat*EE*EE + (size_t)nb*96*EE;
  const float* bias = (mat==0)?bq:(mat==1)?bk:bv;
  bf16_t* outp = (mat==0)?qb:(mat==1)?kb:vb;
  const int t = threadIdx.x, lane = t&63, wid = t>>6;
  const int wr = wid>>1, wc = wid&1;
  const int lrow = lane&15, lk = lane>>4;
  const bf16_t* Ag = xn + (size_t)bm*128*EE;

  const int srow = t>>2, sp = t&3;
  const int sg = sp ^ ((srow>>1)&3);
  const int pcs = (lrow>>1)&3;

  auto stage = [&](int buf, int k0) {
    const bf16_t* asrc = Ag + (size_t)srow*EE + k0 + sg*8;
    const bf16_t* bsrc = W  + (size_t)srow*EE + k0 + sg*8;
    GLDS16(asrc,                 &As[buf][0][0] + t*8);
    GLDS16(asrc + (size_t)64*EE, &As[buf][0][0] + 2048 + t*8);
    GLDS16(bsrc,                 &Bs[buf][0][0] + t*8);
    if (t < 128)
      GLDS16(bsrc + (size_t)64*EE, &Bs[buf][0][0] + 2048 + t*8);
  };

  f32x4 acc[4][3];
  #pragma unroll
  for (int i=0;i<4;++i)
    #pragma unroll
    for (int j=0;j<3;++j) acc[i][j] = (f32x4){0.f,0.f,0.f,0.f};

  stage(0, 0);
  __syncthreads();
  int cur = 0;
  for (int k0=0; k0<EE; k0+=32) {
    if (k0+32 < EE) stage(cur^1, k0+32);
    bf16x8 af[4], bfv[3];
    #pragma unroll
    for (int mi=0;mi<4;++mi) af[mi]  = *(const bf16x8*)&As[cur][wr*64+mi*16+lrow][(lk^pcs)*8];
    #pragma unroll
    for (int ni=0;ni<3;++ni) bfv[ni] = *(const bf16x8*)&Bs[cur][wc*48+ni*16+lrow][(lk^pcs)*8];
    #pragma unroll
    for (int mi=0;mi<4;++mi)
      #pragma unroll
      for (int ni=0;ni<3;++ni)
        acc[mi][ni] = __builtin_amdgcn_mfma_f32_16x16x32_bf16(af[mi], bfv[ni], acc[mi][ni], 0,0,0);
    __syncthreads();
    cur ^= 1;
  }
  const int m_base = bm*128 + wr*64;
  const int n_base = nb*96 + wc*48;
  #pragma unroll
  for (int ni=0;ni<3;++ni) {
    const int col = n_base + ni*16 + lrow;
    const float bias_v = bias[col];
    #pragma unroll
    for (int mi=0;mi<4;++mi) {
      #pragma unroll
      for (int r=0;r<4;++r) {
        int row = m_base + mi*16 + 4*lk + r;
        outp[(size_t)row*EE + col] = (bf16_t)(acc[mi][ni][r] + bias_v);
      }
    }
  }
}

// ---------------- V transpose: v[b,s,h,d] -> vt[(b*H+h)*D + d][s] ----------------
__global__ __launch_bounds__(256) void vtrans_kernel(
    const bf16_t* __restrict__ v, bf16_t* __restrict__ vt)
{
  __shared__ __align__(16) bf16_t tile[64][72];
  const int j0 = blockIdx.x*64, bh = blockIdx.y;
  const int b = bh/HH, h = bh%HH;
  const int t = threadIdx.x;
  #pragma unroll
  for (int it=0; it<2; ++it) {
    int idx = it*256+t, r = idx>>3, c8 = (idx&7)*8;
    *(bf16x8*)&tile[r][c8] = *(const bf16x8*)(v + (size_t)(b*SS + j0 + r)*EE + h*DD + c8);
  }
  __syncthreads();
  #pragma unroll
  for (int it=0; it<2; ++it) {
    int idx = it*256+t, d = idx>>3, c8 = (idx&7)*8;
    bf16x8 val;
    #pragma unroll
    for (int i=0;i<8;++i) val[i] = tile[c8+i][d];
    *(bf16x8*)(vt + ((size_t)bh*DD + d)*SS + j0 + c8) = val;
  }
}

// ---------------- flash attention (anti-causal: attend j >= i) ----------------
// R12 configuration EXACT (best measured). Q-resident j-split: 4 waves, 64
// q-rows/block; each wave holds 4 q-groups' Q fragments in registers and owns
// a 16-j slice of every staged tile. Fixed-max softmax (p=e^(S-24), additive).
__global__ __launch_bounds__(256, 3) void attn_kernel(
    const bf16_t* __restrict__ qb, const bf16_t* __restrict__ kb,
    const bf16_t* __restrict__ vt, bf16_t* __restrict__ hb)
{
  __shared__ __align__(16) bf16_t Ks[2][64][64];   // K tile [j][d]
  __shared__ __align__(16) bf16_t Vts[2][64][64];  // V^T tile [d][j]
  __shared__ __align__(16) float  Osum[64][68];    // O merge [q][d] (+pad)
  __shared__ float Lsum[4][64];                    // lsum partial [wave][q]

  // snake remap: blocks bid, bid+256, bid+512 share a CU -> complementary work
  const int bid = blockIdx.x;
  const int rnd = bid >> 8, g8 = bid & 255;
  const int item = (rnd == 1) ? (511 - g8) : (rnd*256 + g8);
  const int qt = item / 24, bh = item % 24;

  const int i0 = qt*64, b = bh/HH, h = bh%HH;
  const int t = threadIdx.x, lane = t&63, w = t>>6;   // w = wave id = j-slice
  const int lrow = lane&15, lk = lane>>4;

  const int sr = t>>3, sp = t&7;
  const int sgc = sp ^ (sr&7);
  const bf16_t* kbase  = kb + (size_t)b*SS*EE + h*DD;
  const bf16_t* vtbase = vt + (size_t)bh*DD*SS;

  // Q fragments (B-operand), 4 groups of 16 q-rows — loop-invariant registers
  bf16x8 qf[4][2];
  #pragma unroll
  for (int g=0; g<4; ++g) {
    const bf16_t* qrow = qb + (size_t)(b*SS + i0 + g*16 + lrow)*EE + h*DD;
    qf[g][0] = *(const bf16x8*)(qrow + lk*8);
    qf[g][1] = *(const bf16x8*)(qrow + 32 + lk*8);
  }

  f32x4 acc[4][4];
  #pragma unroll
  for (int g=0; g<4; ++g)
    #pragma unroll
    for (int i=0;i<4;++i) acc[g][i] = (f32x4){0.f,0.f,0.f,0.f};
  float lsum[4] = {0.f,0.f,0.f,0.f};
  const int kkey = lrow&7;

  auto stage = [&](int buf, int jt) {
    const int j0v = jt*64;
    const bf16_t* ksrc = kbase  + (size_t)(j0v + sr)*EE + sgc*8;
    const bf16_t* vsrc = vtbase + (size_t)sr*SS + j0v + sgc*8;
    GLDS16(ksrc,                 &Ks[buf][0][0]  + t*8);
    GLDS16(ksrc + (size_t)32*EE, &Ks[buf][0][0]  + 2048 + t*8);
    GLDS16(vsrc,                 &Vts[buf][0][0] + t*8);
    GLDS16(vsrc + (size_t)32*SS, &Vts[buf][0][0] + 2048 + t*8);
  };

  // Per tile, this wave covers j-local = w*16 + 4*lk + r (its 16-j slice).
  // p = e^(qk/8 - 24) = 2^(a*0.1803369 - 34.62468); fixed max -> additive
#define ATTN_TILE(CUR, MASKED) do {                                          \
    const bf16_t* krow = &Ks[CUR][w*16 + lrow][0];                           \
    bf16x8 kf0 = *(const bf16x8*)(krow + ((lk^kkey)<<3));                    \
    bf16x8 kf1 = *(const bf16x8*)(krow + (((lk+4)^kkey)<<3));                \
    bf16x4 pb[4];                                                            \
    _Pragma("unroll")                                                        \
    for (int g=0; g<4; ++g) {                                                \
      f32x4 a = (f32x4){0.f,0.f,0.f,0.f};                                    \
      a = __builtin_amdgcn_mfma_f32_16x16x32_bf16(kf0, qf[g][0], a, 0,0,0);  \
      a = __builtin_amdgcn_mfma_f32_16x16x32_bf16(kf1, qf[g][1], a, 0,0,0);  \
      _Pragma("unroll")                                                      \
      for (int r=0;r<4;++r) {                                                \
        float ee = a[r]*0.180336878f - 34.6246784f;                          \
        if (MASKED && (w*16 + 4*lk + r) < (g*16 + lrow)) ee = -1e30f;        \
        float p = exp2f(ee);                                                 \
        lsum[g] += p;                                                        \
        pb[g][r] = (bf16_t)p;                                                \
      }                                                                      \
    }                                                                        \
    _Pragma("unroll")                                                        \
    for (int sd=0;sd<4;++sd) {                                               \
      const bf16_t* vrow = &Vts[CUR][sd*16+lrow][0];                         \
      bf16x4 vf = *(const bf16x4*)(vrow + (((2*w+(lk>>1))^kkey)<<3) + ((lk&1)<<2)); \
      _Pragma("unroll")                                                      \
      for (int g=0; g<4; ++g)                                                \
        acc[g][sd] = mfma_16x16x16_bf16(vf, pb[g], acc[g][sd]);              \
    }                                                                        \
  } while(0)

  const int ntiles = SS/64 - qt;  // 1..32
  stage(0, qt);
  __syncthreads();                 // buf0 ready
  if (ntiles > 1) stage(1, qt+1);  // prefetch flies under diagonal compute
  ATTN_TILE(0, true);              // diagonal tile, masked
#if !MFMA16_BUILTIN
  asm volatile("s_nop 7\n\ts_nop 7");
#endif
  __syncthreads();

  int cur = 1;
  for (int it2=1; it2<ntiles; ++it2) {
    if (it2+1 < ntiles) stage(cur^1, qt+it2+1);
    ATTN_TILE(cur, false);
#if !MFMA16_BUILTIN
    asm volatile("s_nop 7\n\ts_nop 7");
#endif
    __syncthreads();
    cur ^= 1;
  }
#undef ATTN_TILE

  // lsum: reduce across lk (j within slice); store per-wave partials
  #pragma unroll
  for (int g=0; g<4; ++g) {
    lsum[g] += __shfl_xor(lsum[g], 16);
    lsum[g] += __shfl_xor(lsum[g], 32);
  }
  if (lane < 16) {
    #pragma unroll
    for (int g=0; g<4; ++g) Lsum[w][g*16 + lane] = lsum[g];
  }

  // O merge across waves (each holds a j-partial of the FULL 64q x 64d tile)
  __syncthreads();
  if (w == 0) {
    #pragma unroll
    for (int g=0; g<4; ++g)
      #pragma unroll
      for (int sd=0; sd<4; ++sd)
        *(f32x4*)&Osum[g*16+lrow][sd*16 + 4*lk] = acc[g][sd];
  }
  __syncthreads();
  if (w == 1) {
    #pragma unroll
    for (int g=0; g<4; ++g)
      #pragma unroll
      for (int sd=0; sd<4; ++sd) {
        f32x4 v = *(f32x4*)&Osum[g*16+lrow][sd*16 + 4*lk];
        *(f32x4*)&Osum[g*16+lrow][sd*16 + 4*lk] = v + acc[g][sd];
      }
  }
  __syncthreads();
  if (w == 2) {
    #pragma unroll
    for (int g=0; g<4; ++g)
      #pragma unroll
      for (int sd=0; sd<4; ++sd) {
        f32x4 v = *(f32x4*)&Osum[g*16+lrow][sd*16 + 4*lk];
        *(f32x4*)&Osum[g*16+lrow][sd*16 + 4*lk] = v + acc[g][sd];
      }
  }
  __syncthreads();
  if (w == 3) {
    #pragma unroll
    for (int g=0; g<4; ++g)
      #pragma unroll
      for (int sd=0; sd<4; ++sd) {
        f32x4 v = *(f32x4*)&Osum[g*16+lrow][sd*16 + 4*lk];
        *(f32x4*)&Osum[g*16+lrow][sd*16 + 4*lk] = v + acc[g][sd];
      }
  }
  __syncthreads();

  // final: normalize + coalesced bf16 store (thread t: q = t>>2, 16 d each)
  const int q = t>>2, dq = t&3;
  const float ltot = Lsum[0][q] + Lsum[1][q] + Lsum[2][q] + Lsum[3][q];
  const float inv = 1.0f / ltot;
  bf16_t* orow = hb + (size_t)(b*SS + i0 + q)*EE + h*DD + dq*16;
  bf16x8 o0, o1;
  #pragma unroll
  for (int c=0;c<2;++c) {
    f32x4 v0 = *(const f32x4*)&Osum[q][dq*16 + c*8];
    f32x4 v1 = *(const f32x4*)&Osum[q][dq*16 + c*8 + 4];
    #pragma unroll
    for (int i=0;i<4;++i) {
      if (c==0) { o0[i] = (bf16_t)(v0[i]*inv); o0[i+4] = (bf16_t)(v1[i]*inv); }
      else      { o1[i] = (bf16_t)(v0[i]*inv); o1[i+4] = (bf16_t)(v1[i]*inv); }
    }
  }
  *(bf16x8*)orow = o0;
  *(bf16x8*)(orow+8) = o1;
}

// ---------------- output GEMM: BM=64 BN=48 -> 64x16 = 1024 blocks (4/CU) ----------------
__global__ __launch_bounds__(256) void gemm_out_kernel(
    const bf16_t* __restrict__ hbuf, const bf16_t* __restrict__ wto,
    const float* __restrict__ bo, float* __restrict__ out)
{
  __shared__ __align__(16) bf16_t As[2][64][32];
  __shared__ __align__(16) bf16_t Bs[2][48][32];
  const int bm = blockIdx.x, nb = blockIdx.y;
  const bf16_t* W = wto + (size_t)nb*48*EE;
  const int t = threadIdx.x, lane = t&63, wid = t>>6;
  const int lrow = lane&15, lk = lane>>4;
  const bf16_t* Ag = hbuf + (size_t)bm*64*EE;

  const int srow = t>>2, sp = t&3;
  const int sg = sp ^ ((srow>>1)&3);
  const int pcs = (lrow>>1)&3;

  auto stage = [&](int buf, int k0) {
    GLDS16(Ag + (size_t)srow*EE + k0 + sg*8, &As[buf][0][0] + t*8);
    if (t < 192)
      GLDS16(W + (size_t)srow*EE + k0 + sg*8, &Bs[buf][0][0] + t*8);
  };

  f32x4 acc[3];
  #pragma unroll
  for (int j=0;j<3;++j) acc[j] = (f32x4){0.f,0.f,0.f,0.f};

  stage(0, 0);
  __syncthreads();
  int cur = 0;
  for (int k0=0; k0<EE; k0+=32) {
    if (k0+32 < EE) stage(cur^1, k0+32);
    bf16x8 af, bfv[3];
    af = *(const bf16x8*)&As[cur][wid*16+lrow][(lk^pcs)*8];
    #pragma unroll
    for (int ni=0;ni<3;++ni) bfv[ni] = *(const bf16x8*)&Bs[cur][ni*16+lrow][(lk^pcs)*8];
    #pragma unroll
    for (int ni=0;ni<3;++ni)
      acc[ni] = __builtin_amdgcn_mfma_f32_16x16x32_bf16(af, bfv[ni], acc[ni], 0,0,0);
    __syncthreads();
    cur ^= 1;
  }
  const int m_base = bm*64 + wid*16;
  const int n_base = nb*48;
  #pragma unroll
  for (int ni=0;ni<3;++ni) {
    const int col = n_base + ni*16 + lrow;
    const float bias_v = bo[col];
    #pragma unroll
    for (int r=0;r<4;++r) {
      int row = m_base + 4*lk + r;
      out[(size_t)row*EE + col] = acc[ni][r] + bias_v;
    }
  }
}

extern "C" void kernel_launch(void* const* d_in, const int* in_sizes, int n_in,
                              void* d_out, int out_size, void* d_ws, size_t ws_size,
                              hipStream_t stream) {
  const float* x    = (const float*)d_in[0];
  const float* ln_w = (const float*)d_in[1];
  const float* ln_b = (const float*)d_in[2];
  const float* wq   = (const float*)d_in[3];
  const float* bq   = (const float*)d_in[4];
  const float* wk   = (const float*)d_in[5];
  const float* bk   = (const float*)d_in[6];
  const float* wv   = (const float*)d_in[7];
  const float* bv   = (const float*)d_in[8];
  const float* wo   = (const float*)d_in[9];
  const float* bo   = (const float*)d_in[10];
  float* out = (float*)d_out;

  char* ws = (char*)d_ws;
  bf16_t* wt  = (bf16_t*)(ws);
  bf16_t* xn  = (bf16_t*)(ws + 4718592);
  bf16_t* qb  = (bf16_t*)(ws + 11010048);
  bf16_t* kb  = (bf16_t*)(ws + 17301504);
  bf16_t* vb  = (bf16_t*)(ws + 23592960);
  bf16_t* vtb = (bf16_t*)(ws + 29884416);
  bf16_t* hb  = (bf16_t*)(ws + 36175872);

  prep_kernel    <<<dim3(1600),    256, 0, stream>>>(wq, wk, wv, wo, wt, x, ln_w, ln_b, xn);
  gemm_qkv_kernel<<<dim3(32,24),   256, 0, stream>>>(xn, wt, bq, bk, bv, qb, kb, vb);
  vtrans_kernel  <<<dim3(32,24),   256, 0, stream>>>(vb, vtb);
  attn_kernel    <<<dim3(768),     256, 0, stream>>>(qb, kb, vtb, hb);
  gemm_out_kernel<<<dim3(64,16),   256, 0, stream>>>(hb, wt + (size_t)3*EE*EE, bo, out);
}